// Round 4
// baseline (358.909 us; speedup 1.0000x reference)
//
#include <hip/hip_runtime.h>
#include <cstdint>
#include <cstddef>

typedef unsigned short u16;
typedef unsigned int u32;
typedef __attribute__((ext_vector_type(8))) short shortx8;
typedef __attribute__((ext_vector_type(4))) float floatx4;

__device__ __forceinline__ u16 f2b(float f) {
    u32 b = __float_as_uint(f);
    b += 0x7fffu + ((b >> 16) & 1u);   // RNE
    return (u16)(b >> 16);
}

// ================= uprep body: all weight-space pushdown precompute =================
// uw layout (floats):
//   [0,128)    u31 = W31 @ Wr3[0:64]
//   [128,256)  u32 = W32 @ Wr3[64:128]
//   [256]      c3  = b31.Wr3a + b32.Wr3b + br3
//   [257,260)  c2v = b21.{Wr2a,u31a,u32a} + b22.{Wr2b,u31b,u32b}
//   [260,708)  m1c[7][64]: col0 = W11@Wr1a; col j = W11@H[j-1][0:64]
//   [708,1156) m2c[7][64]: col0 = W12@Wr1b; col j = W12@H[j-1][64:128]
//   [1156,1163) C[7]: C[j] = b11.S_j[0:64] + b12.S_j[64:128], S_0=Wr1, S_j=H[j-1]
__device__ void uprep_body(const float* __restrict__ W11, const float* __restrict__ W12,
                           const float* __restrict__ W21, const float* __restrict__ W22,
                           const float* __restrict__ W31, const float* __restrict__ W32,
                           const float* __restrict__ b11, const float* __restrict__ b12,
                           const float* __restrict__ b21, const float* __restrict__ b22,
                           const float* __restrict__ b31, const float* __restrict__ b32,
                           const float* __restrict__ Wr1, const float* __restrict__ Wr2,
                           const float* __restrict__ Wr3, const float* __restrict__ br3,
                           float* __restrict__ uw, float* H /* [6][128] LDS */) {
    int t = threadIdx.x;
    // Stage A: u31/u32
    if (t < 128) {
        float a = 0.f, b = 0.f;
        for (int c = 0; c < 64; ++c) {
            a = fmaf(W31[t * 64 + c], Wr3[c], a);
            b = fmaf(W32[t * 64 + c], Wr3[64 + c], b);
        }
        uw[t] = a;
        uw[128 + t] = b;
    }
    __syncthreads();
    // Stage B: 6 H vectors, 128 entries each
    for (int it = t; it < 768; it += 256) {
        int v = it >> 7;     // which vector
        int k = it & 127;    // row of W21/W22
        const float* W = (v < 3) ? W21 : W22;
        const float* s;
        switch (v % 3) { case 0: s = Wr2; break; case 1: s = uw; break; default: s = uw + 128; }
        int so = (v < 3) ? 0 : 64;
        float acc = 0.f;
        for (int c = 0; c < 64; ++c) acc = fmaf(W[k * 64 + c], s[so + c], acc);
        H[v * 128 + k] = acc;
    }
    __syncthreads();
    // Stage C: m1c / m2c (7 columns x 64)
    for (int it = t; it < 7 * 64; it += 256) {
        int j = it >> 6, i = it & 63;
        float a1 = 0.f, a2 = 0.f;
        if (j == 0) {
            for (int c = 0; c < 64; ++c) {
                a1 = fmaf(W11[i * 64 + c], Wr1[c], a1);
                a2 = fmaf(W12[i * 64 + c], Wr1[64 + c], a2);
            }
        } else {
            const float* h = &H[(j - 1) * 128];
            for (int c = 0; c < 64; ++c) {
                a1 = fmaf(W11[i * 64 + c], h[c], a1);
                a2 = fmaf(W12[i * 64 + c], h[64 + c], a2);
            }
        }
        uw[260 + j * 64 + i] = a1;
        uw[708 + j * 64 + i] = a2;
    }
    // Stage D: scalar constants (wave 0 only; disjoint uw ranges from stage C)
    if (t < 64) {
        float bb1 = b11[t], bb2 = b12[t];
        float r;
#define REDW(VAL, IDX)                                                  \
        { r = (VAL);                                                    \
          for (int o = 32; o > 0; o >>= 1) r += __shfl_down(r, o);      \
          if (t == 0) uw[IDX] = r; }
        REDW(bb1 * Wr1[t] + bb2 * Wr1[64 + t], 1156)
        REDW(bb1 * H[0 * 128 + t] + bb2 * H[0 * 128 + 64 + t], 1157)
        REDW(bb1 * H[1 * 128 + t] + bb2 * H[1 * 128 + 64 + t], 1158)
        REDW(bb1 * H[2 * 128 + t] + bb2 * H[2 * 128 + 64 + t], 1159)
        REDW(bb1 * H[3 * 128 + t] + bb2 * H[3 * 128 + 64 + t], 1160)
        REDW(bb1 * H[4 * 128 + t] + bb2 * H[4 * 128 + 64 + t], 1161)
        REDW(bb1 * H[5 * 128 + t] + bb2 * H[5 * 128 + 64 + t], 1162)
        float c1 = b21[t], c2 = b22[t];
        REDW(c1 * Wr2[t] + c2 * Wr2[64 + t], 257)
        REDW(c1 * uw[t] + c2 * uw[64 + t], 258)
        REDW(c1 * uw[128 + t] + c2 * uw[192 + t], 259)
        REDW(b31[t] * Wr3[t] + b32[t] * Wr3[64 + t], 256)
        if (t == 0) uw[256] += br3[0];
#undef REDW
    }
}

// ================= prep: degree count (direct atomics) + uprep rider block =================
__global__ __launch_bounds__(256) void prep(const int* __restrict__ ei1, const int* __restrict__ ei2,
                                            int* __restrict__ deg,
                                            const float* __restrict__ W11, const float* __restrict__ W12,
                                            const float* __restrict__ W21, const float* __restrict__ W22,
                                            const float* __restrict__ W31, const float* __restrict__ W32,
                                            const float* __restrict__ b11, const float* __restrict__ b12,
                                            const float* __restrict__ b21, const float* __restrict__ b22,
                                            const float* __restrict__ b31, const float* __restrict__ b32,
                                            const float* __restrict__ Wr1, const float* __restrict__ Wr2,
                                            const float* __restrict__ Wr3, const float* __restrict__ br3,
                                            float* __restrict__ uw,
                                            int N, int E1, int E2, int gE) {
    __shared__ float H[6 * 128];
    if ((int)blockIdx.x < gE) {
        int e = blockIdx.x * 256 + threadIdx.x;
        if (e < E1) {
            atomicAdd(&deg[ei1[E1 + e]], 1);
        } else if (e < E1 + E2) {
            int i = e - E1;
            atomicAdd(&deg[N + ei2[E2 + i]], 1);
        }
    } else {
        uprep_body(W11, W12, W21, W22, W31, W32, b11, b12, b21, b22, b31, b32,
                   Wr1, Wr2, Wr3, br3, uw, H);
    }
}

// ================= scans over deg[2N] =================
__global__ void scan1(const int* __restrict__ deg, int* __restrict__ partial, int n) {
    __shared__ int s[256];
    int i = blockIdx.x * 256 + threadIdx.x;
    s[threadIdx.x] = (i < n) ? deg[i] : 0;
    __syncthreads();
    for (int off = 128; off > 0; off >>= 1) {
        if (threadIdx.x < off) s[threadIdx.x] += s[threadIdx.x + off];
        __syncthreads();
    }
    if (threadIdx.x == 0) partial[blockIdx.x] = s[0];
}

__global__ void scan2(int* __restrict__ partial, int nb, int* __restrict__ starts, int n) {
    __shared__ int s[256];
    __shared__ int carry;
    int t = threadIdx.x;
    if (t == 0) carry = 0;
    __syncthreads();
    for (int c0 = 0; c0 < nb; c0 += 256) {
        int i = c0 + t;
        int v = (i < nb) ? partial[i] : 0;
        s[t] = v;
        __syncthreads();
        for (int off = 1; off < 256; off <<= 1) {
            int u = (t >= off) ? s[t - off] : 0;
            __syncthreads();
            s[t] += u;
            __syncthreads();
        }
        if (i < nb) partial[i] = carry + s[t] - v;   // exclusive
        __syncthreads();
        if (t == 255) carry += s[255];
        __syncthreads();
    }
    if (t == 0) starts[n] = carry;
}

// scan3: exclusive starts + cursor copy + dinv (rsqrt of deg) in one pass
__global__ void scan3(const int* __restrict__ deg, const int* __restrict__ partial,
                      int* __restrict__ starts, int* __restrict__ cur,
                      float* __restrict__ dinv1, float* __restrict__ dinv2, int n, int N) {
    __shared__ int s[256];
    int i = blockIdx.x * 256 + threadIdx.x;
    int v = (i < n) ? deg[i] : 0;
    s[threadIdx.x] = v;
    __syncthreads();
    for (int off = 1; off < 256; off <<= 1) {
        int u = (threadIdx.x >= off) ? s[threadIdx.x - off] : 0;
        __syncthreads();
        s[threadIdx.x] += u;
        __syncthreads();
    }
    if (i < n) {
        int st = partial[blockIdx.x] + s[threadIdx.x] - v;
        starts[i] = st;
        cur[i] = st;
        float dv = v > 0 ? rsqrtf((float)v) : 0.f;
        if (i < N) dinv1[i] = dv;
        else dinv2[i - N] = dv;
    }
}

// ================= placeMM: mmR0 blocks first, then CSR-place blocks =================
// mmR0: R0 = relu(x@Win + b) + readout0 + source-side payloads s1p/s2p (dinv-scaled).
// place: csr[atomicAdd(cur[col])] = row (u16).
__global__ __launch_bounds__(256) void placeMM(const float* __restrict__ x,
                                               const float* __restrict__ W_in,
                                               const float* __restrict__ b_in,
                                               const float* __restrict__ dinv1,
                                               const float* __restrict__ dinv2,
                                               float* __restrict__ s1p,
                                               float* __restrict__ s2p,
                                               const float* __restrict__ Wr0,
                                               const float* __restrict__ br0,
                                               const float* __restrict__ br1,
                                               const float* __restrict__ br2,
                                               const float* __restrict__ w0,
                                               const float* __restrict__ w1,
                                               const float* __restrict__ w2,
                                               const float* __restrict__ w3,
                                               const float* __restrict__ uw,
                                               float* __restrict__ outacc,
                                               const int* __restrict__ ei1, const int* __restrict__ ei2,
                                               int* __restrict__ cur, u16* __restrict__ csr,
                                               int n, int gMM, int E1, int E2, int N) {
    constexpr int LDA = 72;
    __shared__ u16 As[64 * LDA];     // x (bf16), later overwritten by R0 (wave-private rows)
    __shared__ u16 W0s[64 * LDA];
    __shared__ float Ms[2][8][64];   // m1c / m2c with zero-padded col 7

    if ((int)blockIdx.x >= gMM) {
        // ---- place role ----
        int e = (blockIdx.x - gMM) * 256 + threadIdx.x;
        if (e < E1) {
            int r = ei1[e], c = ei1[E1 + e];
            int pos = atomicAdd(&cur[c], 1);
            csr[pos] = (u16)r;
        } else if (e < E1 + E2) {
            int i = e - E1;
            int r = ei2[i], c = ei2[E2 + i];
            int pos = atomicAdd(&cur[N + c], 1);
            csr[pos] = (u16)r;
        }
        return;
    }

    // ---- mmR0 role ----
    const int tid = threadIdx.x;
    const int r0 = blockIdx.x * 64;

    for (int idx = tid; idx < 64 * 16; idx += 256) {
        int r = idx >> 4, q4 = (idx & 15) * 4;
        int gr = r0 + r;
        float4 v = {0, 0, 0, 0};
        if (gr < n) v = *(const float4*)&x[(size_t)gr * 64 + q4];
        ushort4 o = {f2b(v.x), f2b(v.y), f2b(v.z), f2b(v.w)};
        *(ushort4*)&As[r * LDA + q4] = o;
    }
    for (int idx = tid; idx < 16 * 64; idx += 256) {
        int k = idx >> 4, qc = idx & 15;
        float4 a = *(const float4*)&W_in[k * 64 + 4 * qc];
        W0s[(4*qc+0) * LDA + k] = f2b(a.x); W0s[(4*qc+1) * LDA + k] = f2b(a.y);
        W0s[(4*qc+2) * LDA + k] = f2b(a.z); W0s[(4*qc+3) * LDA + k] = f2b(a.w);
    }
    for (int idx = tid; idx < 896; idx += 256) {
        int mat = idx / 448, rem = idx % 448;
        Ms[mat][rem >> 6][rem & 63] = uw[260 + idx];
    }
    for (int idx = tid; idx < 128; idx += 256) {
        Ms[idx >> 6][7][idx & 63] = 0.f;     // pad column
    }
    __syncthreads();

    const int wave = tid >> 6;
    const int lane = tid & 63;
    const int m = lane & 15;
    const int ko = (lane >> 4) * 8;
    floatx4 z4 = {0.f, 0.f, 0.f, 0.f};
    floatx4 accR[4] = {z4, z4, z4, z4};

#pragma unroll
    for (int kc = 0; kc < 64; kc += 32) {
        shortx8 af = *(shortx8*)&As[(wave * 16 + m) * LDA + kc + ko];
#pragma unroll
        for (int nt = 0; nt < 4; ++nt) {
            shortx8 bf = *(shortx8*)&W0s[(nt * 16 + m) * LDA + kc + ko];
            accR[nt] = __builtin_amdgcn_mfma_f32_16x16x32_bf16(af, bf, accR[nt], 0, 0, 0);
        }
    }

    float bv[4], wr0[4];
#pragma unroll
    for (int nt = 0; nt < 4; ++nt) {
        bv[nt] = b_in[nt * 16 + m];
        wr0[nt] = Wr0[nt * 16 + m];
    }
    const int lrow = wave * 16 + (lane >> 4) * 4;
    float W0c = w0[0];
    // uw[1156] = b11.Wr1a + b12.Wr1b (readout1 bias const); uw[256] = c3
    float CONST = W0c * br0[0] + w1[0] * (br1[0] + uw[1156]) + w2[0] * br2[0] + w3[0] * uw[256];
#pragma unroll
    for (int rg = 0; rg < 4; ++rg) {
        int gr = r0 + lrow + rg;
        float p = 0.f;
#pragma unroll
        for (int nt = 0; nt < 4; ++nt) {
            float v = fmaxf(accR[nt][rg] + bv[nt], 0.f);
            As[(lrow + rg) * LDA + nt * 16 + m] = f2b(v);   // R0 (bf16) back into LDS
            p = fmaf(v, wr0[nt], p);
        }
#pragma unroll
        for (int off = 8; off > 0; off >>= 1) p += __shfl_down(p, off);
        if (m == 0 && gr < n) outacc[gr] = W0c * p + CONST;
    }
    // No barrier: each wave reads only its own 16 rows of As below (written by this wave).

    // Payload phase: lane handles (row = lane&15, quarter q = lane>>4).
    // q0: s1 cols 0-3, q1: s1 cols 4-7(pad), q2: s2 cols 0-3, q3: s2 cols 4-7(pad).
    {
        int prow = lane & 15;
        int q = lane >> 4;
        int row = wave * 16 + prow;
        const float* Mc = &Ms[q >> 1][(q & 1) * 4][0];
        float p0 = 0.f, p1 = 0.f, p2 = 0.f, p3 = 0.f;
#pragma unroll
        for (int kc = 0; kc < 64; kc += 8) {
            shortx8 rv = *(shortx8*)&As[row * LDA + kc];
#pragma unroll
            for (int t = 0; t < 8; ++t) {
                float f = __uint_as_float(((u32)(u16)rv[t]) << 16);
                p0 = fmaf(f, Mc[0 * 64 + kc + t], p0);
                p1 = fmaf(f, Mc[1 * 64 + kc + t], p1);
                p2 = fmaf(f, Mc[2 * 64 + kc + t], p2);
                p3 = fmaf(f, Mc[3 * 64 + kc + t], p3);
            }
        }
        int gr = r0 + row;
        if (gr < n) {
            float dsc = (q < 2) ? dinv1[gr] : dinv2[gr];   // source-side norm folded in
            float* dst = ((q < 2) ? s1p : s2p) + (size_t)gr * 8 + (q & 1) * 4;
            *(float4*)dst = make_float4(dsc * p0, dsc * p1, dsc * p2, dsc * p3);
        }
    }
}

// ================= gatherP: both-set scalar-payload gather + epilogue ================
// One wave per destination. Half-wave per set; 16 edge slots in flight; 2 lanes per edge
// (part = float4 half of the 8-float payload). No per-edge weight (folded into payload).
__global__ __launch_bounds__(256) void gatherP(const int* __restrict__ starts,
                                               const u16* __restrict__ csr,
                                               const float* __restrict__ s1p,
                                               const float* __restrict__ s2p,
                                               const float* __restrict__ dinv1,
                                               const float* __restrict__ dinv2,
                                               const float* __restrict__ uw,
                                               float4* __restrict__ sA,
                                               float4* __restrict__ sB,
                                               float* __restrict__ pr, int N) {
    int d = (blockIdx.x * blockDim.x + threadIdx.x) >> 6;
    int lane = threadIdx.x & 63;
    if (d >= N) return;
    int half = lane >> 5;
    int slot = (lane & 31) >> 1;
    int part = lane & 1;
    int base = half ? N : 0;
    int e0 = starts[base + d];
    int e1 = starts[base + d + 1];
    const float* S = half ? s2p : s1p;
    float ax = 0.f, ay = 0.f, az = 0.f, aw = 0.f;
    for (int j = e0 + slot; j < e1; j += 16) {
        u32 src = csr[j];
        float4 pv = *(const float4*)&S[(size_t)src * 8 + part * 4];
        ax += pv.x; ay += pv.y; az += pv.z; aw += pv.w;
    }
#pragma unroll
    for (int off = 2; off <= 16; off <<= 1) {
        ax += __shfl_down(ax, off);
        ay += __shfl_down(ay, off);
        az += __shfl_down(az, off);
        aw += __shfl_down(aw, off);
    }
    // lanes 0/1 hold set-1 comps {0-3}/{4-7}; lanes 32/33 hold set-2 comps.
    float bx = __shfl(ax, lane + 32);
    float by = __shfl(ay, lane + 32);
    float bz = __shfl(az, lane + 32);
    float bw = __shfl(aw, lane + 32);
    if (lane < 2) {
        float da = dinv1[d], db = dinv2[d];
        float d0 = da * ax + db * bx;
        float d1 = da * ay + db * by;
        float d2 = da * az + db * bz;
        float d3 = da * aw + db * bw;
        const float* C = uw + 1156;
        if (lane == 0) {
            pr[d] = d0;    // dj[0] (readout1 dot, bias already in CONST)
            sA[d] = make_float4(da * (d1 + C[1]), da * (d2 + C[2]), da * (d3 + C[3]), 0.f);
        } else {
            sB[d] = make_float4(db * (d0 + C[4]), db * (d1 + C[5]), db * (d2 + C[6]), 0.f);
        }
    }
}

// ================= gatherS: 2 destinations per wave; 16 lanes per (dest,set) =================
__global__ __launch_bounds__(256) void gatherS(const int* __restrict__ starts,
                                               const u16* __restrict__ csr,
                                               const float4* __restrict__ sA,
                                               const float4* __restrict__ sB,
                                               const float* __restrict__ pr,
                                               const float* __restrict__ dinv1,
                                               const float* __restrict__ dinv2,
                                               const float* __restrict__ w1,
                                               const float* __restrict__ w2,
                                               const float* __restrict__ w3,
                                               const float* __restrict__ c2v,
                                               float* __restrict__ outacc,
                                               float* __restrict__ z1, float* __restrict__ z2, int N) {
    int wid = (blockIdx.x * blockDim.x + threadIdx.x) >> 6;
    int lane = threadIdx.x & 63;
    int g = lane >> 5;          // dest slot within wave
    int sub = lane & 31;
    int set = sub >> 4;
    int l16 = sub & 15;
    int d = wid * 2 + g;
    float p = 0.f, q1 = 0.f, q2 = 0.f;
    if (d < N) {
        int base = set ? N : 0;
        int e0 = starts[base + d];
        int e1 = starts[base + d + 1];
        const float4* S = set ? sB : sA;
        for (int j = e0 + l16; j < e1; j += 16) {
            float4 s = S[csr[j]];
            p += s.x; q1 += s.y; q2 += s.z;
        }
    }
#pragma unroll
    for (int off = 8; off > 0; off >>= 1) {
        p += __shfl_down(p, off); q1 += __shfl_down(q1, off); q2 += __shfl_down(q2, off);
    }
    // lane g*32 holds set-1 sums; lane g*32+16 holds set-2 sums
    float pB  = __shfl(p,  lane + 16);
    float qB1 = __shfl(q1, lane + 16);
    float qB2 = __shfl(q2, lane + 16);
    if (sub == 0 && d < N) {
        float da = dinv1[d], db = dinv2[d];
        float pp  = da * p  + db * pB;
        float qq1 = da * q1 + db * qB1;
        float qq2 = da * q2 + db * qB2;
        float W3 = w3[0];
        outacc[d] += w1[0] * pr[d] + w2[0] * (pp + c2v[0]);
        z1[d] = da * (W3 * (qq1 + c2v[1]));   // pre-scaled by dinv1 for gather3's source role
        z2[d] = db * (W3 * (qq2 + c2v[2]));
    }
}

// ================= gather3: 2 destinations per wave; 16 lanes per (dest,set) =================
__global__ __launch_bounds__(256) void gather3(const int* __restrict__ starts,
                                               const u16* __restrict__ csr,
                                               const float* __restrict__ z1,
                                               const float* __restrict__ z2,
                                               const float* __restrict__ dinv1,
                                               const float* __restrict__ dinv2,
                                               const float* __restrict__ outacc,
                                               float* __restrict__ out, int N) {
    int wid = (blockIdx.x * blockDim.x + threadIdx.x) >> 6;
    int lane = threadIdx.x & 63;
    int g = lane >> 5;
    int sub = lane & 31;
    int set = sub >> 4;
    int l16 = sub & 15;
    int d = wid * 2 + g;
    float acc = 0.f;
    if (d < N) {
        int base = set ? N : 0;
        int e0 = starts[base + d];
        int e1 = starts[base + d + 1];
        const float* Z = set ? z2 : z1;
        for (int j = e0 + l16; j < e1; j += 16) acc += Z[csr[j]];
    }
#pragma unroll
    for (int off = 8; off > 0; off >>= 1) acc += __shfl_down(acc, off);
    float accB = __shfl(acc, lane + 16);
    if (sub == 0 && d < N)
        out[d] = outacc[d] + dinv1[d] * acc + dinv2[d] * accB;
}

// ================= host =================
static inline char* carve(char*& p, size_t bytes) {
    char* r = p;
    p += (bytes + 255) & ~(size_t)255;
    return r;
}

extern "C" void kernel_launch(void* const* d_in, const int* in_sizes, int n_in,
                              void* d_out, int out_size, void* d_ws, size_t ws_size,
                              hipStream_t stream) {
    const float* x    = (const float*)d_in[0];
    const int*   ei1  = (const int*)d_in[1];
    const int*   ei2  = (const int*)d_in[2];
    const float* W_in = (const float*)d_in[3];  const float* b_in = (const float*)d_in[4];
    const float* W11  = (const float*)d_in[5];
    const float* b11  = (const float*)d_in[6];
    const float* W12  = (const float*)d_in[7];  const float* b12  = (const float*)d_in[8];
    const float* W21  = (const float*)d_in[9];  const float* b21  = (const float*)d_in[10];
    const float* W22  = (const float*)d_in[11]; const float* b22  = (const float*)d_in[12];
    const float* W31  = (const float*)d_in[13]; const float* b31  = (const float*)d_in[14];
    const float* W32  = (const float*)d_in[15]; const float* b32  = (const float*)d_in[16];
    const float* Wr0  = (const float*)d_in[17]; const float* br0  = (const float*)d_in[18];
    const float* Wr1  = (const float*)d_in[19]; const float* br1  = (const float*)d_in[20];
    const float* Wr2  = (const float*)d_in[21]; const float* br2  = (const float*)d_in[22];
    const float* Wr3  = (const float*)d_in[23]; const float* br3  = (const float*)d_in[24];
    const float* w0   = (const float*)d_in[25];
    const float* w1   = (const float*)d_in[26];
    const float* w2   = (const float*)d_in[27];
    const float* w3   = (const float*)d_in[28];

    const int N  = in_sizes[0] / 64;   // 50000 (fits u16)
    const int E1 = in_sizes[1] / 2;    // 800000
    const int E2 = in_sizes[2] / 2;
    const int Etot = E1 + E2;
    const int N2 = 2 * N;

    char* p = (char*)d_ws;
    float*  dinv1   = (float*)carve(p, (size_t)N * 4);
    float*  dinv2   = (float*)carve(p, (size_t)N * 4);
    int*    deg     = (int*)  carve(p, (size_t)N2 * 4);
    int*    starts  = (int*)  carve(p, ((size_t)N2 + 1) * 4);
    int*    cur     = (int*)  carve(p, (size_t)N2 * 4);
    int*    partial = (int*)  carve(p, 2048 * 4);
    float*  uws     = (float*)carve(p, 1200 * 4);                // pushdown precompute block
    float*  z       = (float*)carve(p, (size_t)N2 * 4);          // z1 | z2
    float*  pr      = (float*)carve(p, (size_t)N * 4);           // readout1 per node
    float4* sA      = (float4*)carve(p, (size_t)N * 16);
    float4* sB      = (float4*)carve(p, (size_t)N * 16);
    u16*    csr     = (u16*)  carve(p, (size_t)Etot * 2);        // src index only (u16: N<65536)
    float*  s1p     = (float*)carve(p, (size_t)N * 8 * 4);       // source payloads (dinv1-scaled)
    float*  s2p     = (float*)carve(p, (size_t)N * 8 * 4);       // source payloads (dinv2-scaled)
    float*  outacc  = (float*)carve(p, (size_t)N * 4);
    float*  c2v = uws + 257;
    float*  z1 = z, *z2 = z + N;
    (void)ws_size; (void)n_in; (void)out_size;

    const int B = 256;
    dim3 blk(B);
    int gE   = (Etot + B - 1) / B;                                 // edge blocks (prep / place)
    int gMM  = (N + 63) / 64;
    int gG   = (int)(((long long)N * 64 + B - 1) / B);             // 1 dest/wave (gatherP)
    int gG2  = (int)(((long long)((N + 1) / 2) * 64 + B - 1) / B); // 2 dests/wave (gatherS/3)
    int nb2  = (N2 + 255) / 256;                                   // scan blocks over deg[2N]

    // ---- degree count (direct atomics) + weight-space precompute rider ----
    hipMemsetAsync(deg, 0, (size_t)N2 * 4, stream);
    prep<<<gE + 1, blk, 0, stream>>>(ei1, ei2, deg,
                                     W11, W12, W21, W22, W31, W32,
                                     b11, b12, b21, b22, b31, b32,
                                     Wr1, Wr2, Wr3, br3, uws, N, E1, E2, gE);

    // ---- exclusive scan over deg -> starts / cur / dinv ----
    scan1<<<nb2, blk, 0, stream>>>(deg, partial, N2);
    scan2<<<1, 256, 0, stream>>>(partial, nb2, starts, N2);
    scan3<<<nb2, blk, 0, stream>>>(deg, partial, starts, cur, dinv1, dinv2, N2, N);

    // ---- R0 matmul + payload pushdown (blocks first) + CSR place (atomic cursors) ----
    placeMM<<<gMM + gE, blk, 0, stream>>>(x, W_in, b_in, dinv1, dinv2, s1p, s2p,
                                          Wr0, br0, br1, br2, w0, w1, w2, w3, uws, outacc,
                                          ei1, ei2, cur, csr, N, gMM, E1, E2, N);

    // ---- layers 1+2 fused: 8-float payload gather (both sets) + pushdown epilogue ----
    gatherP<<<gG, blk, 0, stream>>>(starts, csr, s1p, s2p, dinv1, dinv2, uws, sA, sB, pr, N);

    // ---- layer 2 gather of scalar payloads ----
    gatherS<<<gG2, blk, 0, stream>>>(starts, csr, sA, sB, pr, dinv1, dinv2,
                                     w1, w2, w3, c2v, outacc, z1, z2, N);

    // ---- layer 3 (algebraic shortcut): out = outacc + dinv*gather(z') ----
    gather3<<<gG2, blk, 0, stream>>>(starts, csr, z1, z2, dinv1, dinv2, outacc, (float*)d_out, N);
}

// Round 5
// 232.791 us; speedup vs baseline: 1.5418x; 1.5418x over previous
//
#include <hip/hip_runtime.h>
#include <cstdint>
#include <cstddef>

typedef unsigned short u16;
typedef unsigned int u32;
typedef __attribute__((ext_vector_type(8))) short shortx8;
typedef __attribute__((ext_vector_type(4))) float floatx4;

#define SLICES 128

__device__ __forceinline__ u16 f2b(float f) {
    u32 b = __float_as_uint(f);
    b += 0x7fffu + ((b >> 16) & 1u);   // RNE
    return (u16)(b >> 16);
}

// ================= uprep body: all weight-space pushdown precompute =================
// uw layout (floats):
//   [0,128)    u31 = W31 @ Wr3[0:64]
//   [128,256)  u32 = W32 @ Wr3[64:128]
//   [256]      c3  = b31.Wr3a + b32.Wr3b + br3
//   [257,260)  c2v = b21.{Wr2a,u31a,u32a} + b22.{Wr2b,u31b,u32b}
//   [260,708)  m1c[7][64]: col0 = W11@Wr1a; col j = W11@H[j-1][0:64]
//   [708,1156) m2c[7][64]: col0 = W12@Wr1b; col j = W12@H[j-1][64:128]
//   [1156,1163) C[7]: C[j] = b11.S_j[0:64] + b12.S_j[64:128], S_0=Wr1, S_j=H[j-1]
__device__ void uprep_body(const float* __restrict__ W11, const float* __restrict__ W12,
                           const float* __restrict__ W21, const float* __restrict__ W22,
                           const float* __restrict__ W31, const float* __restrict__ W32,
                           const float* __restrict__ b11, const float* __restrict__ b12,
                           const float* __restrict__ b21, const float* __restrict__ b22,
                           const float* __restrict__ b31, const float* __restrict__ b32,
                           const float* __restrict__ Wr1, const float* __restrict__ Wr2,
                           const float* __restrict__ Wr3, const float* __restrict__ br3,
                           float* __restrict__ uw, float* H /* [6][128] LDS */) {
    int t = threadIdx.x;
    // Stage A: u31/u32
    if (t < 128) {
        float a = 0.f, b = 0.f;
        for (int c = 0; c < 64; ++c) {
            a = fmaf(W31[t * 64 + c], Wr3[c], a);
            b = fmaf(W32[t * 64 + c], Wr3[64 + c], b);
        }
        uw[t] = a;
        uw[128 + t] = b;
    }
    __syncthreads();
    // Stage B: 6 H vectors, 128 entries each
    for (int it = t; it < 768; it += 256) {
        int v = it >> 7;     // which vector
        int k = it & 127;    // row of W21/W22
        const float* W = (v < 3) ? W21 : W22;
        const float* s;
        switch (v % 3) { case 0: s = Wr2; break; case 1: s = uw; break; default: s = uw + 128; }
        int so = (v < 3) ? 0 : 64;
        float acc = 0.f;
        for (int c = 0; c < 64; ++c) acc = fmaf(W[k * 64 + c], s[so + c], acc);
        H[v * 128 + k] = acc;
    }
    __syncthreads();
    // Stage C: m1c / m2c (7 columns x 64)
    for (int it = t; it < 7 * 64; it += 256) {
        int j = it >> 6, i = it & 63;
        float a1 = 0.f, a2 = 0.f;
        if (j == 0) {
            for (int c = 0; c < 64; ++c) {
                a1 = fmaf(W11[i * 64 + c], Wr1[c], a1);
                a2 = fmaf(W12[i * 64 + c], Wr1[64 + c], a2);
            }
        } else {
            const float* h = &H[(j - 1) * 128];
            for (int c = 0; c < 64; ++c) {
                a1 = fmaf(W11[i * 64 + c], h[c], a1);
                a2 = fmaf(W12[i * 64 + c], h[64 + c], a2);
            }
        }
        uw[260 + j * 64 + i] = a1;
        uw[708 + j * 64 + i] = a2;
    }
    // Stage D: scalar constants (wave 0 only; disjoint uw ranges from stage C)
    if (t < 64) {
        float bb1 = b11[t], bb2 = b12[t];
        float r;
#define REDW(VAL, IDX)                                                  \
        { r = (VAL);                                                    \
          for (int o = 32; o > 0; o >>= 1) r += __shfl_down(r, o);      \
          if (t == 0) uw[IDX] = r; }
        REDW(bb1 * Wr1[t] + bb2 * Wr1[64 + t], 1156)
        REDW(bb1 * H[0 * 128 + t] + bb2 * H[0 * 128 + 64 + t], 1157)
        REDW(bb1 * H[1 * 128 + t] + bb2 * H[1 * 128 + 64 + t], 1158)
        REDW(bb1 * H[2 * 128 + t] + bb2 * H[2 * 128 + 64 + t], 1159)
        REDW(bb1 * H[3 * 128 + t] + bb2 * H[3 * 128 + 64 + t], 1160)
        REDW(bb1 * H[4 * 128 + t] + bb2 * H[4 * 128 + 64 + t], 1161)
        REDW(bb1 * H[5 * 128 + t] + bb2 * H[5 * 128 + 64 + t], 1162)
        float c1 = b21[t], c2 = b22[t];
        REDW(c1 * Wr2[t] + c2 * Wr2[64 + t], 257)
        REDW(c1 * uw[t] + c2 * uw[64 + t], 258)
        REDW(c1 * uw[128 + t] + c2 * uw[192 + t], 259)
        REDW(b31[t] * Wr3[t] + b32[t] * Wr3[64 + t], 256)
        if (t == 0) uw[256] += br3[0];
#undef REDW
    }
}

// ================= histU: per-(bucket,slice) histogram + uprep rider block =================
__global__ __launch_bounds__(256) void histU(const int* __restrict__ ei1, const int* __restrict__ ei2,
                                             int* __restrict__ pcnt,
                                             const float* __restrict__ W11, const float* __restrict__ W12,
                                             const float* __restrict__ W21, const float* __restrict__ W22,
                                             const float* __restrict__ W31, const float* __restrict__ W32,
                                             const float* __restrict__ b11, const float* __restrict__ b12,
                                             const float* __restrict__ b21, const float* __restrict__ b22,
                                             const float* __restrict__ b31, const float* __restrict__ b32,
                                             const float* __restrict__ Wr1, const float* __restrict__ Wr2,
                                             const float* __restrict__ Wr3, const float* __restrict__ br3,
                                             float* __restrict__ uw,
                                             int NB, int E1, int E2) {
    __shared__ u32 h[512];
    __shared__ float H[6 * 128];
    if ((int)blockIdx.x >= 2 * SLICES) {
        uprep_body(W11, W12, W21, W22, W31, W32, b11, b12, b21, b22, b31, b32,
                   Wr1, Wr2, Wr3, br3, uw, H);
        return;
    }
    int set = blockIdx.x >> 7;
    int s = blockIdx.x & (SLICES - 1);
    const int* col = set ? ei2 + E2 : ei1 + E1;
    int E = set ? E2 : E1;
    for (int i = threadIdx.x; i < NB; i += 256) h[i] = 0;
    __syncthreads();
    int esz = (E + SLICES - 1) / SLICES;
    int e0 = s * esz, e1 = min(e0 + esz, E);
    for (int e = e0 + threadIdx.x; e < e1; e += 256)
        atomicAdd(&h[col[e] >> 7], 1u);
    __syncthreads();
    for (int b = threadIdx.x; b < NB; b += 256)
        pcnt[(size_t)(set * NB + b) * SLICES + s] = (int)h[b];
}

// ================= scans (pcnt, in place) =================
__global__ void scan1(const int* __restrict__ deg, int* __restrict__ partial, int n) {
    __shared__ int s[256];
    int i = blockIdx.x * 256 + threadIdx.x;
    s[threadIdx.x] = (i < n) ? deg[i] : 0;
    __syncthreads();
    for (int off = 128; off > 0; off >>= 1) {
        if (threadIdx.x < off) s[threadIdx.x] += s[threadIdx.x + off];
        __syncthreads();
    }
    if (threadIdx.x == 0) partial[blockIdx.x] = s[0];
}

__global__ void scan2(int* __restrict__ partial, int nb, int* __restrict__ starts, int n) {
    __shared__ int s[256];
    __shared__ int carry;
    int t = threadIdx.x;
    if (t == 0) carry = 0;
    __syncthreads();
    for (int c0 = 0; c0 < nb; c0 += 256) {
        int i = c0 + t;
        int v = (i < nb) ? partial[i] : 0;
        s[t] = v;
        __syncthreads();
        for (int off = 1; off < 256; off <<= 1) {
            int u = (t >= off) ? s[t - off] : 0;
            __syncthreads();
            s[t] += u;
            __syncthreads();
        }
        if (i < nb) partial[i] = carry + s[t] - v;   // exclusive
        __syncthreads();
        if (t == 255) carry += s[255];
        __syncthreads();
    }
    if (t == 0) starts[n] = carry;
}

__global__ void scan3(const int* __restrict__ deg, const int* __restrict__ partial,
                      int* __restrict__ starts, int n) {
    __shared__ int s[256];
    int i = blockIdx.x * 256 + threadIdx.x;
    int v = (i < n) ? deg[i] : 0;
    s[threadIdx.x] = v;
    __syncthreads();
    for (int off = 1; off < 256; off <<= 1) {
        int u = (threadIdx.x >= off) ? s[threadIdx.x - off] : 0;
        __syncthreads();
        s[threadIdx.x] += u;
        __syncthreads();
    }
    if (i < n) starts[i] = partial[blockIdx.x] + s[threadIdx.x] - v;
}

// ================= partMM: mmR0 blocks first, then radix-partition blocks =================
// mmR0: R0 = relu(x@Win + b) + readout0 + UNSCALED source payloads s1p/s2p
//       (dinv[src] applied per-edge in gatherP, removing the fill3->mmR0 dependency).
// part: bucket-partition edges into eord via per-(bucket,slice) LDS cursors (coalesced writes).
__global__ __launch_bounds__(256) void partMM(const float* __restrict__ x,
                                              const float* __restrict__ W_in,
                                              const float* __restrict__ b_in,
                                              float* __restrict__ s1p,
                                              float* __restrict__ s2p,
                                              const float* __restrict__ Wr0,
                                              const float* __restrict__ br0,
                                              const float* __restrict__ br1,
                                              const float* __restrict__ br2,
                                              const float* __restrict__ w0,
                                              const float* __restrict__ w1,
                                              const float* __restrict__ w2,
                                              const float* __restrict__ w3,
                                              const float* __restrict__ uw,
                                              float* __restrict__ outacc,
                                              const int* __restrict__ ei1, const int* __restrict__ ei2,
                                              const int* __restrict__ poffs, u32* __restrict__ eord,
                                              int n, int gMM, int NB, int E1, int E2) {
    constexpr int LDA = 72;
    __shared__ u16 As[64 * LDA];     // x (bf16), later overwritten by R0 (wave-private rows)
    __shared__ u16 W0s[64 * LDA];
    __shared__ float Msw[64][17];    // payload matrix, k-major, odd stride (bank-conflict-free)
    __shared__ u32 curL[512];

    if ((int)blockIdx.x >= gMM) {
        // ---- part role ----
        int pb = blockIdx.x - gMM;
        int set = pb >> 7;
        int s = pb & (SLICES - 1);
        const int* rows = set ? ei2 : ei1;
        int E = set ? E2 : E1;
        const int* cols = rows + E;
        for (int b = threadIdx.x; b < NB; b += 256)
            curL[b] = (u32)poffs[(size_t)(set * NB + b) * SLICES + s];
        __syncthreads();
        int esz = (E + SLICES - 1) / SLICES;
        int e0 = s * esz, e1 = min(e0 + esz, E);
        for (int e = e0 + threadIdx.x; e < e1; e += 256) {
            int c = cols[e];
            u32 pos = atomicAdd(&curL[c >> 7], 1u);
            eord[pos] = ((u32)rows[e] << 7) | (u32)(c & 127);
        }
        return;
    }

    // ---- mmR0 role ----
    const int tid = threadIdx.x;
    const int r0 = blockIdx.x * 64;

    for (int idx = tid; idx < 64 * 16; idx += 256) {
        int r = idx >> 4, q4 = (idx & 15) * 4;
        int gr = r0 + r;
        float4 v = {0, 0, 0, 0};
        if (gr < n) v = *(const float4*)&x[(size_t)gr * 64 + q4];
        ushort4 o = {f2b(v.x), f2b(v.y), f2b(v.z), f2b(v.w)};
        *(ushort4*)&As[r * LDA + q4] = o;
    }
    for (int idx = tid; idx < 16 * 64; idx += 256) {
        int k = idx >> 4, qc = idx & 15;
        float4 a = *(const float4*)&W_in[k * 64 + 4 * qc];
        W0s[(4*qc+0) * LDA + k] = f2b(a.x); W0s[(4*qc+1) * LDA + k] = f2b(a.y);
        W0s[(4*qc+2) * LDA + k] = f2b(a.z); W0s[(4*qc+3) * LDA + k] = f2b(a.w);
    }
    // Msw[k][colIdx]: colIdx 0..6 = m1c cols, 7 = pad, 8..14 = m2c cols, 15 = pad
    for (int idx = tid; idx < 896; idx += 256) {
        int mat = idx / 448, rem = idx % 448;
        Msw[rem & 63][mat * 8 + (rem >> 6)] = uw[260 + idx];
    }
    for (int idx = tid; idx < 128; idx += 256) {
        Msw[idx & 63][(idx >> 6) * 8 + 7] = 0.f;   // pad columns
    }
    __syncthreads();

    const int wave = tid >> 6;
    const int lane = tid & 63;
    const int m = lane & 15;
    const int ko = (lane >> 4) * 8;
    floatx4 z4 = {0.f, 0.f, 0.f, 0.f};
    floatx4 accR[4] = {z4, z4, z4, z4};

#pragma unroll
    for (int kc = 0; kc < 64; kc += 32) {
        shortx8 af = *(shortx8*)&As[(wave * 16 + m) * LDA + kc + ko];
#pragma unroll
        for (int nt = 0; nt < 4; ++nt) {
            shortx8 bf = *(shortx8*)&W0s[(nt * 16 + m) * LDA + kc + ko];
            accR[nt] = __builtin_amdgcn_mfma_f32_16x16x32_bf16(af, bf, accR[nt], 0, 0, 0);
        }
    }

    float bv[4], wr0[4];
#pragma unroll
    for (int nt = 0; nt < 4; ++nt) {
        bv[nt] = b_in[nt * 16 + m];
        wr0[nt] = Wr0[nt * 16 + m];
    }
    const int lrow = wave * 16 + (lane >> 4) * 4;
    float W0c = w0[0];
    // uw[1156] = b11.Wr1a + b12.Wr1b (readout1 bias const); uw[256] = c3
    float CONST = W0c * br0[0] + w1[0] * (br1[0] + uw[1156]) + w2[0] * br2[0] + w3[0] * uw[256];
#pragma unroll
    for (int rg = 0; rg < 4; ++rg) {
        int gr = r0 + lrow + rg;
        float p = 0.f;
#pragma unroll
        for (int nt = 0; nt < 4; ++nt) {
            float v = fmaxf(accR[nt][rg] + bv[nt], 0.f);
            As[(lrow + rg) * LDA + nt * 16 + m] = f2b(v);   // R0 (bf16) back into LDS
            p = fmaf(v, wr0[nt], p);
        }
#pragma unroll
        for (int off = 8; off > 0; off >>= 1) p += __shfl_down(p, off);
        if (m == 0 && gr < n) outacc[gr] = W0c * p + CONST;
    }
    // No barrier: each wave reads only its own 16 rows of As below (written by this wave).

    // Payload phase: lane handles (row = lane&15, quarter q = lane>>4).
    // q0: s1 cols 0-3, q1: s1 cols 4-7(pad), q2: s2 cols 0-3, q3: s2 cols 4-7(pad).
    {
        int prow = lane & 15;
        int q = lane >> 4;
        int row = wave * 16 + prow;
        const int cb = (q >> 1) * 8 + (q & 1) * 4;
        float p0 = 0.f, p1 = 0.f, p2 = 0.f, p3 = 0.f;
#pragma unroll
        for (int kc = 0; kc < 64; kc += 8) {
            shortx8 rv = *(shortx8*)&As[row * LDA + kc];
#pragma unroll
            for (int t = 0; t < 8; ++t) {
                float f = __uint_as_float(((u32)(u16)rv[t]) << 16);
                p0 = fmaf(f, Msw[kc + t][cb + 0], p0);
                p1 = fmaf(f, Msw[kc + t][cb + 1], p1);
                p2 = fmaf(f, Msw[kc + t][cb + 2], p2);
                p3 = fmaf(f, Msw[kc + t][cb + 3], p3);
            }
        }
        int gr = r0 + row;
        if (gr < n) {
            float* dst = ((q < 2) ? s1p : s2p) + (size_t)gr * 8 + (q & 1) * 4;
            *(float4*)dst = make_float4(p0, p1, p2, p3);   // UNSCALED (dinv applied in gatherP)
        }
    }
}

// fill3: counts bins (emits dinv + starts), LDS-caches the bucket's eord chunk during the
// count pass so the place pass reads LDS instead of re-streaming global; writes u16 csr.
#define F3CAP 5120
__global__ __launch_bounds__(256) void fill3(const u32* __restrict__ eord,
                                             const int* __restrict__ poffs,
                                             int* __restrict__ starts,
                                             u16* __restrict__ csr,
                                             float* __restrict__ d1, float* __restrict__ d2,
                                             int N, int NB) {
    __shared__ u32 cacheE[F3CAP];
    __shared__ u32 cnt[128];
    __shared__ int sc[128];
    __shared__ u32 cur[128];
    int set = blockIdx.x >= NB;
    int bucket = set ? blockIdx.x - NB : blockIdx.x;
    if (threadIdx.x < 128) cnt[threadIdx.x] = 0;
    __syncthreads();
    int s0 = poffs[(size_t)(set * NB + bucket) * SLICES];
    int s1 = poffs[(size_t)(set * NB + bucket + 1) * SLICES];
    for (int j = s0 + threadIdx.x; j < s1; j += 256) {
        u32 e = eord[j];
        int o = j - s0;
        if (o < F3CAP) cacheE[o] = e;
        atomicAdd(&cnt[e & 127], 1u);
    }
    __syncthreads();
    if (threadIdx.x < 128) sc[threadIdx.x] = (int)cnt[threadIdx.x];
    __syncthreads();
    for (int off = 1; off < 128; off <<= 1) {
        int u = (threadIdx.x < 128 && threadIdx.x >= off) ? sc[threadIdx.x - off] : 0;
        __syncthreads();
        if (threadIdx.x < 128) sc[threadIdx.x] += u;
        __syncthreads();
    }
    if (threadIdx.x < 128) {
        u32 st = (u32)s0 + (u32)(sc[threadIdx.x] - (int)cnt[threadIdx.x]);  // exclusive
        cur[threadIdx.x] = st;
        int bin = bucket * 128 + threadIdx.x;
        if (bin < N) {
            starts[set * N + bin] = (int)st;
            u32 d = cnt[threadIdx.x];
            float v = d > 0 ? rsqrtf((float)d) : 0.f;
            if (set) d2[bin] = v;
            else d1[bin] = v;
        }
    }
    if (blockIdx.x == 2 * NB - 1 && threadIdx.x == 0) starts[2 * N] = s1;
    __syncthreads();
    for (int j = s0 + threadIdx.x; j < s1; j += 256) {
        int o = j - s0;
        u32 e = (o < F3CAP) ? cacheE[o] : eord[j];
        u32 pos = atomicAdd(&cur[e & 127], 1u);
        csr[pos] = (u16)(e >> 7);
    }
}

// ================= gatherP: both-set payload gather + epilogue ================
// One wave per destination. Half-wave per set; 16 edge slots in flight; 2 lanes per edge.
// Payload is UNSCALED; per-edge weight = dinv_set[src] applied here.
__global__ __launch_bounds__(256) void gatherP(const int* __restrict__ starts,
                                               const u16* __restrict__ csr,
                                               const float* __restrict__ s1p,
                                               const float* __restrict__ s2p,
                                               const float* __restrict__ dinv1,
                                               const float* __restrict__ dinv2,
                                               const float* __restrict__ uw,
                                               float4* __restrict__ sA,
                                               float4* __restrict__ sB,
                                               float* __restrict__ pr, int N) {
    int d = (blockIdx.x * blockDim.x + threadIdx.x) >> 6;
    int lane = threadIdx.x & 63;
    if (d >= N) return;
    int half = lane >> 5;
    int slot = (lane & 31) >> 1;
    int part = lane & 1;
    int base = half ? N : 0;
    int e0 = starts[base + d];
    int e1 = starts[base + d + 1];
    const float* S = half ? s2p : s1p;
    const float* D = half ? dinv2 : dinv1;
    float ax = 0.f, ay = 0.f, az = 0.f, aw = 0.f;
    for (int j = e0 + slot; j < e1; j += 16) {
        u32 src = csr[j];
        float w = D[src];
        float4 pv = *(const float4*)&S[(size_t)src * 8 + part * 4];
        ax = fmaf(w, pv.x, ax); ay = fmaf(w, pv.y, ay);
        az = fmaf(w, pv.z, az); aw = fmaf(w, pv.w, aw);
    }
#pragma unroll
    for (int off = 2; off <= 16; off <<= 1) {
        ax += __shfl_down(ax, off);
        ay += __shfl_down(ay, off);
        az += __shfl_down(az, off);
        aw += __shfl_down(aw, off);
    }
    // lanes 0/1 hold set-1 comps {0-3}/{4-7}; lanes 32/33 hold set-2 comps.
    float bx = __shfl(ax, lane + 32);
    float by = __shfl(ay, lane + 32);
    float bz = __shfl(az, lane + 32);
    float bw = __shfl(aw, lane + 32);
    if (lane < 2) {
        float da = dinv1[d], db = dinv2[d];
        float d0 = da * ax + db * bx;
        float d1 = da * ay + db * by;
        float d2 = da * az + db * bz;
        float d3 = da * aw + db * bw;
        const float* C = uw + 1156;
        if (lane == 0) {
            pr[d] = d0;    // dj[0] (readout1 dot, bias already in CONST)
            sA[d] = make_float4(da * (d1 + C[1]), da * (d2 + C[2]), da * (d3 + C[3]), 0.f);
        } else {
            sB[d] = make_float4(db * (d0 + C[4]), db * (d1 + C[5]), db * (d2 + C[6]), 0.f);
        }
    }
}

// ================= gatherS: 2 destinations per wave; 16 lanes per (dest,set) =================
__global__ __launch_bounds__(256) void gatherS(const int* __restrict__ starts,
                                               const u16* __restrict__ csr,
                                               const float4* __restrict__ sA,
                                               const float4* __restrict__ sB,
                                               const float* __restrict__ pr,
                                               const float* __restrict__ dinv1,
                                               const float* __restrict__ dinv2,
                                               const float* __restrict__ w1,
                                               const float* __restrict__ w2,
                                               const float* __restrict__ w3,
                                               const float* __restrict__ c2v,
                                               float* __restrict__ outacc,
                                               float* __restrict__ z1, float* __restrict__ z2, int N) {
    int wid = (blockIdx.x * blockDim.x + threadIdx.x) >> 6;
    int lane = threadIdx.x & 63;
    int g = lane >> 5;          // dest slot within wave
    int sub = lane & 31;
    int set = sub >> 4;
    int l16 = sub & 15;
    int d = wid * 2 + g;
    float p = 0.f, q1 = 0.f, q2 = 0.f;
    if (d < N) {
        int base = set ? N : 0;
        int e0 = starts[base + d];
        int e1 = starts[base + d + 1];
        const float4* S = set ? sB : sA;
        for (int j = e0 + l16; j < e1; j += 16) {
            float4 s = S[csr[j]];
            p += s.x; q1 += s.y; q2 += s.z;
        }
    }
#pragma unroll
    for (int off = 8; off > 0; off >>= 1) {
        p += __shfl_down(p, off); q1 += __shfl_down(q1, off); q2 += __shfl_down(q2, off);
    }
    // lane g*32 holds set-1 sums; lane g*32+16 holds set-2 sums
    float pB  = __shfl(p,  lane + 16);
    float qB1 = __shfl(q1, lane + 16);
    float qB2 = __shfl(q2, lane + 16);
    if (sub == 0 && d < N) {
        float da = dinv1[d], db = dinv2[d];
        float pp  = da * p  + db * pB;
        float qq1 = da * q1 + db * qB1;
        float qq2 = da * q2 + db * qB2;
        float W3 = w3[0];
        outacc[d] += w1[0] * pr[d] + w2[0] * (pp + c2v[0]);
        z1[d] = da * (W3 * (qq1 + c2v[1]));   // pre-scaled by dinv1 for gather3's source role
        z2[d] = db * (W3 * (qq2 + c2v[2]));
    }
}

// ================= gather3: 2 destinations per wave; 16 lanes per (dest,set) =================
__global__ __launch_bounds__(256) void gather3(const int* __restrict__ starts,
                                               const u16* __restrict__ csr,
                                               const float* __restrict__ z1,
                                               const float* __restrict__ z2,
                                               const float* __restrict__ dinv1,
                                               const float* __restrict__ dinv2,
                                               const float* __restrict__ outacc,
                                               float* __restrict__ out, int N) {
    int wid = (blockIdx.x * blockDim.x + threadIdx.x) >> 6;
    int lane = threadIdx.x & 63;
    int g = lane >> 5;
    int sub = lane & 31;
    int set = sub >> 4;
    int l16 = sub & 15;
    int d = wid * 2 + g;
    float acc = 0.f;
    if (d < N) {
        int base = set ? N : 0;
        int e0 = starts[base + d];
        int e1 = starts[base + d + 1];
        const float* Z = set ? z2 : z1;
        for (int j = e0 + l16; j < e1; j += 16) acc += Z[csr[j]];
    }
#pragma unroll
    for (int off = 8; off > 0; off >>= 1) acc += __shfl_down(acc, off);
    float accB = __shfl(acc, lane + 16);
    if (sub == 0 && d < N)
        out[d] = outacc[d] + dinv1[d] * acc + dinv2[d] * accB;
}

// ================= host =================
static inline char* carve(char*& p, size_t bytes) {
    char* r = p;
    p += (bytes + 255) & ~(size_t)255;
    return r;
}

extern "C" void kernel_launch(void* const* d_in, const int* in_sizes, int n_in,
                              void* d_out, int out_size, void* d_ws, size_t ws_size,
                              hipStream_t stream) {
    const float* x    = (const float*)d_in[0];
    const int*   ei1  = (const int*)d_in[1];
    const int*   ei2  = (const int*)d_in[2];
    const float* W_in = (const float*)d_in[3];  const float* b_in = (const float*)d_in[4];
    const float* W11  = (const float*)d_in[5];
    const float* b11  = (const float*)d_in[6];
    const float* W12  = (const float*)d_in[7];  const float* b12  = (const float*)d_in[8];
    const float* W21  = (const float*)d_in[9];  const float* b21  = (const float*)d_in[10];
    const float* W22  = (const float*)d_in[11]; const float* b22  = (const float*)d_in[12];
    const float* W31  = (const float*)d_in[13]; const float* b31  = (const float*)d_in[14];
    const float* W32  = (const float*)d_in[15]; const float* b32  = (const float*)d_in[16];
    const float* Wr0  = (const float*)d_in[17]; const float* br0  = (const float*)d_in[18];
    const float* Wr1  = (const float*)d_in[19]; const float* br1  = (const float*)d_in[20];
    const float* Wr2  = (const float*)d_in[21]; const float* br2  = (const float*)d_in[22];
    const float* Wr3  = (const float*)d_in[23]; const float* br3  = (const float*)d_in[24];
    const float* w0   = (const float*)d_in[25];
    const float* w1   = (const float*)d_in[26];
    const float* w2   = (const float*)d_in[27];
    const float* w3   = (const float*)d_in[28];

    const int N  = in_sizes[0] / 64;   // 50000 (fits u16)
    const int E1 = in_sizes[1] / 2;    // 800000
    const int E2 = in_sizes[2] / 2;
    const int Etot = E1 + E2;
    const int N2 = 2 * N;
    const int NB = (N + 127) >> 7;     // 128-node buckets per set
    const int NP = 2 * NB * SLICES;    // pcnt element count

    char* p = (char*)d_ws;
    float*  dinv1   = (float*)carve(p, (size_t)N * 4);
    float*  dinv2   = (float*)carve(p, (size_t)N * 4);
    int*    pcnt    = (int*)  carve(p, ((size_t)NP + 1) * 4);    // scanned in place -> poffs
    u32*    eord    = (u32*)  carve(p, (size_t)Etot * 4);        // packed (r<<7 | c&127)
    int*    starts  = (int*)  carve(p, ((size_t)N2 + 1) * 4);
    int*    partial = (int*)  carve(p, 2048 * 4);
    float*  uws     = (float*)carve(p, 1200 * 4);                // pushdown precompute block
    float*  z       = (float*)carve(p, (size_t)N2 * 4);          // z1 | z2
    float*  pr      = (float*)carve(p, (size_t)N * 4);           // readout1 per node
    float4* sA      = (float4*)carve(p, (size_t)N * 16);
    float4* sB      = (float4*)carve(p, (size_t)N * 16);
    u16*    csr     = (u16*)  carve(p, (size_t)Etot * 2);        // src index only (u16: N<65536)
    float*  s1p     = (float*)carve(p, (size_t)N * 8 * 4);       // source payloads (unscaled)
    float*  s2p     = (float*)carve(p, (size_t)N * 8 * 4);       // source payloads (unscaled)
    float*  outacc  = (float*)carve(p, (size_t)N * 4);
    float*  c2v = uws + 257;
    float*  z1 = z, *z2 = z + N;
    (void)ws_size; (void)n_in; (void)out_size;

    const int B = 256;
    dim3 blk(B);
    int gMM  = (N + 63) / 64;
    int gG   = (int)(((long long)N * 64 + B - 1) / B);             // 1 dest/wave (gatherP)
    int gG2  = (int)(((long long)((N + 1) / 2) * 64 + B - 1) / B); // 2 dests/wave (gatherS/3)
    int nbP  = (NP + 255) / 256;

    // ---- histogram (radix, LDS atomics) + weight-space precompute rider ----
    histU<<<2 * SLICES + 1, blk, 0, stream>>>(ei1, ei2, pcnt,
                                              W11, W12, W21, W22, W31, W32,
                                              b11, b12, b21, b22, b31, b32,
                                              Wr1, Wr2, Wr3, br3, uws, NB, E1, E2);

    // ---- exclusive scan of pcnt (in place -> poffs) ----
    scan1<<<nbP, blk, 0, stream>>>(pcnt, partial, NP);
    scan2<<<1, 256, 0, stream>>>(partial, nbP, pcnt, NP);
    scan3<<<nbP, blk, 0, stream>>>(pcnt, partial, pcnt, NP);

    // ---- R0 matmul + payload pushdown (blocks first) + bucket partition (rider) ----
    partMM<<<gMM + 2 * SLICES, blk, 0, stream>>>(x, W_in, b_in, s1p, s2p,
                                                 Wr0, br0, br1, br2, w0, w1, w2, w3, uws, outacc,
                                                 ei1, ei2, pcnt, eord, N, gMM, NB, E1, E2);

    // ---- within-bucket count/place -> starts, dinv, u16 csr ----
    fill3<<<2 * NB, blk, 0, stream>>>(eord, pcnt, starts, csr, dinv1, dinv2, N, NB);

    // ---- layers 1+2 fused: payload gather (both sets, dinv[src] per edge) + epilogue ----
    gatherP<<<gG, blk, 0, stream>>>(starts, csr, s1p, s2p, dinv1, dinv2, uws, sA, sB, pr, N);

    // ---- layer 2 gather of scalar payloads ----
    gatherS<<<gG2, blk, 0, stream>>>(starts, csr, sA, sB, pr, dinv1, dinv2,
                                     w1, w2, w3, c2v, outacc, z1, z2, N);

    // ---- layer 3 (algebraic shortcut): out = outacc + dinv*gather(z') ----
    gather3<<<gG2, blk, 0, stream>>>(starts, csr, z1, z2, dinv1, dinv2, outacc, (float*)d_out, N);
}